// Round 1
// baseline (258.514 us; speedup 1.0000x reference)
//
#include <hip/hip_runtime.h>
#include <hip/hip_fp16.h>

#define B_ 4
#define S_ 2048
#define H_ 1024
#define M_ (B_ * S_)  // 8192 flattened rows of x / q / k / v

typedef _Float16 f16;
typedef _Float16 f16x8 __attribute__((ext_vector_type(8)));
typedef _Float16 f16x4 __attribute__((ext_vector_type(4)));
typedef float f32x4 __attribute__((ext_vector_type(4)));

typedef __attribute__((address_space(3))) unsigned int* lds_u32p;
typedef const __attribute__((address_space(1))) unsigned int* gbl_u32p;

// async global->LDS, 16B per lane; LDS dest is wave-uniform base + lane*16
__device__ __forceinline__ void stage16(const f16* g, f16* l) {
  __builtin_amdgcn_global_load_lds((gbl_u32p)g, (lds_u32p)l, 16, 0, 0);
}

// ---------------------------------------------------------------------------
// One launch: x (8192 blocks) then Wq/Wk/Wv (1024 blocks each) -> fp16 RNE.
__global__ __launch_bounds__(256) void downconvert_all(
    const float* __restrict__ x, const float* __restrict__ W0,
    const float* __restrict__ W1, const float* __restrict__ W2,
    f16* __restrict__ xh, f16* __restrict__ Wh) {
  const int b = blockIdx.x;
  const float* src;
  f16* dst;
  long i;
  if (b < M_ * H_ / 1024) {  // 8192 x-blocks
    src = x; dst = xh;
    i = (long)b * 256 + threadIdx.x;
  } else {
    const int wb = b - M_ * H_ / 1024;
    const int sel = wb >> 10;               // 1024 blocks per W
    src = sel == 0 ? W0 : (sel == 1 ? W1 : W2);
    dst = Wh + (long)sel * H_ * H_;
    i = (long)(wb & 1023) * 256 + threadIdx.x;
  }
  f32x4 v = ((const f32x4*)src)[i];
  f16x4 h;
#pragma unroll
  for (int c = 0; c < 4; c++) h[c] = (f16)v[c];
  ((f16x4*)dst)[i] = h;
}

// ---------------------------------------------------------------------------
// 256x256-tile phase-interleaved NT fp16 GEMM (T2+T3+T4+T5 stack).
// K fixed at 1024, BK=32, 32 K-tiles, 4 LDS buffers (4 x (16K A + 16K B) =
// 128 KiB). 512 threads = 8 waves as 2(M)x4(N); per-wave output 128x64.
// Per K-tile: 2 phases x 16 MFMA; per phase: ds_reads + 2 global_load_lds
// (staging K-tile kt+3 into buffer (kt+3)&3, which was fully consumed at
// K-tile kt-1 -> race-free 3-tile-deep pipeline), raw s_barrier, lgkmcnt(0),
// setprio-wrapped MFMA cluster. Counted s_waitcnt vmcnt(8) once per K-tile
// (tail: 4, 0). LDS swizzle: 16B-chunk c at row r holds global chunk
// c ^ ((r>>1)&3); applied on the global SOURCE address of global_load_lds
// (LDS dest stays linear, m104/m173) and on the ds_read address -> 2 lanes
// per 16B granule = conflict-free.
// EPI=0: scores (C = f16(acc*alpha), per-z batch). EPI=1: qkv projection
// (bias add, f16; sel==2 (V) written transposed to vT).
template <int EPI>
__global__ __launch_bounds__(512, 2)
void gemm8p(const f16* __restrict__ A, const f16* __restrict__ Bm,
            const float* __restrict__ bq, const float* __restrict__ bk,
            const float* __restrict__ bv, f16* __restrict__ out,
            f16* __restrict__ vT, float alpha) {
  __shared__ __align__(16) f16 LA[4][256 * 32];
  __shared__ __align__(16) f16 LB[4][256 * 32];
  const int t = threadIdx.x;
  const int wv = t >> 6, lane = t & 63;
  const int quad = lane >> 4, l16 = lane & 15;
  const int wm = (wv >> 2) * 128;  // 0 / 128
  const int wn = (wv & 3) * 64;    // 0..192

  int bm, bn, sel = 0;
  const f16 *Ab, *Bb;
  if (EPI == 1) {
    bm = blockIdx.x * 256;               // 0..8191 (32 tiles)
    sel = blockIdx.y >> 2;               // 0=q 1=k 2=v
    bn = (blockIdx.y & 3) * 256;         // 0..1023
    Ab = A + (long)bm * H_;
    Bb = Bm + (long)sel * H_ * H_ + (long)bn * H_;
  } else {
    bm = blockIdx.x * 256;               // 0..2047
    bn = blockIdx.y * 256;               // 0..2047
    Ab = A + (long)blockIdx.z * S_ * H_ + (long)bm * H_;
    Bb = Bm + (long)blockIdx.z * S_ * H_ + (long)bn * H_;
  }

  // staging addressing: thread t covers 16B chunks t (rows 0..127) and
  // 512+t (rows 128..255); both have the same in-row chunk and swizzle.
  const int srow = t >> 2;
  const int sch = (t & 3) ^ ((srow >> 1) & 3);  // pre-swizzled source chunk
  const long goff = (long)srow * H_ + sch * 8;  // element offset (lda==H_)
  const int loff = t * 8;                       // LDS element offset (linear)

  // ds_read addressing: frag row = w? + i*16 + l16; (row>>1)&3 == (l16>>1)&3
  const int swz = quad ^ ((l16 >> 1) & 3);
  const int aoff = (wm + l16) * 32 + swz * 8;
  const int boff = (wn + l16) * 32 + swz * 8;

  f32x4 acc[8][4] = {};

  // prologue: stage K-tiles 0..2 (12 loads; order A0 A1 B0 B1 per tile)
#pragma unroll
  for (int p = 0; p < 3; ++p) {
    stage16(Ab + goff + p * 32, &LA[p][loff]);
    stage16(Ab + goff + 128 * H_ + p * 32, &LA[p][loff + 4096]);
    stage16(Bb + goff + p * 32, &LB[p][loff]);
    stage16(Bb + goff + 128 * H_ + p * 32, &LB[p][loff + 4096]);
  }

#define KT_BODY(kt, VM, DO_STAGE)                                             \
  {                                                                           \
    asm volatile("s_waitcnt vmcnt(" #VM ")" ::: "memory");                    \
    __builtin_amdgcn_s_barrier();                                             \
    const int buf_ = (kt) & 3;                                                \
    const f16* LAb = LA[buf_];                                                \
    const f16* LBb = LB[buf_];                                                \
    f16x8 af[4], bf[4], ag[4];                                                \
    _Pragma("unroll") for (int mi = 0; mi < 4; ++mi)                          \
        af[mi] = *(const f16x8*)&LAb[aoff + mi * 512];                        \
    _Pragma("unroll") for (int ni = 0; ni < 4; ++ni)                          \
        bf[ni] = *(const f16x8*)&LBb[boff + ni * 512];                        \
    if (DO_STAGE) {                                                           \
      stage16(Ab + goff + ((kt) + 3) * 32, &LA[((kt) + 3) & 3][loff]);        \
      stage16(Ab + goff + 128 * H_ + ((kt) + 3) * 32,                         \
              &LA[((kt) + 3) & 3][loff + 4096]);                              \
    }                                                                         \
    __builtin_amdgcn_s_barrier();                                             \
    asm volatile("s_waitcnt lgkmcnt(0)" ::: "memory");                        \
    __builtin_amdgcn_sched_barrier(0);                                        \
    __builtin_amdgcn_s_setprio(1);                                            \
    _Pragma("unroll") for (int mi = 0; mi < 4; ++mi)                          \
        _Pragma("unroll") for (int ni = 0; ni < 4; ++ni)                      \
            acc[mi][ni] = __builtin_amdgcn_mfma_f32_16x16x32_f16(             \
                af[mi], bf[ni], acc[mi][ni], 0, 0, 0);                        \
    __builtin_amdgcn_s_setprio(0);                                            \
    _Pragma("unroll") for (int mi = 0; mi < 4; ++mi)                          \
        ag[mi] = *(const f16x8*)&LAb[aoff + 2048 + mi * 512];                 \
    if (DO_STAGE) {                                                           \
      stage16(Bb + goff + ((kt) + 3) * 32, &LB[((kt) + 3) & 3][loff]);        \
      stage16(Bb + goff + 128 * H_ + ((kt) + 3) * 32,                         \
              &LB[((kt) + 3) & 3][loff + 4096]);                              \
    }                                                                         \
    __builtin_amdgcn_s_barrier();                                             \
    asm volatile("s_waitcnt lgkmcnt(0)" ::: "memory");                        \
    __builtin_amdgcn_sched_barrier(0);                                        \
    __builtin_amdgcn_s_setprio(1);                                            \
    _Pragma("unroll") for (int mi = 0; mi < 4; ++mi)                          \
        _Pragma("unroll") for (int ni = 0; ni < 4; ++ni)                      \
            acc[mi + 4][ni] = __builtin_amdgcn_mfma_f32_16x16x32_f16(         \
                ag[mi], bf[ni], acc[mi + 4][ni], 0, 0, 0);                    \
    __builtin_amdgcn_s_setprio(0);                                            \
  }

#pragma unroll 4
  for (int kt = 0; kt < 29; ++kt) KT_BODY(kt, 8, 1)
  KT_BODY(29, 8, 0)
  KT_BODY(30, 4, 0)
  KT_BODY(31, 0, 0)
#undef KT_BODY

  if (EPI == 0) {
    f16* C = out + (long)blockIdx.z * S_ * S_;
#pragma unroll
    for (int mi = 0; mi < 8; ++mi)
#pragma unroll
      for (int ni = 0; ni < 4; ++ni) {
        const long m = bm + wm + mi * 16 + quad * 4;
        const long n = bn + wn + ni * 16 + l16;
#pragma unroll
        for (int r = 0; r < 4; ++r)
          C[(m + r) * S_ + n] = (f16)(acc[mi][ni][r] * alpha);
      }
  } else {
    const float* bias = sel == 0 ? bq : (sel == 1 ? bk : bv);
    if (sel == 2) {
      // V transposed: vT[(b*H + n)*S + t_pos], b = m>>11, t_pos = m&2047.
#pragma unroll
      for (int ni = 0; ni < 4; ++ni) {
        const int n = bn + wn + ni * 16 + l16;
        const float bb = bias[n];
#pragma unroll
        for (int mi = 0; mi < 8; ++mi) {
          const int m = bm + wm + mi * 16 + quad * 4;
          f16x4 pack;
#pragma unroll
          for (int r = 0; r < 4; ++r) pack[r] = (f16)(acc[mi][ni][r] + bb);
          *(f16x4*)&vT[((long)(m >> 11) * H_ + n) * S_ + (m & 2047)] = pack;
        }
      }
    } else {
      f16* C = out + (long)sel * M_ * H_;
#pragma unroll
      for (int ni = 0; ni < 4; ++ni) {
        const int n = bn + wn + ni * 16 + l16;
        const float bb = bias[n];
#pragma unroll
        for (int mi = 0; mi < 8; ++mi) {
          const long m = bm + wm + mi * 16 + quad * 4;
#pragma unroll
          for (int r = 0; r < 4; ++r)
            C[(m + r) * H_ + n] = (f16)(acc[mi][ni][r] + bb);
        }
      }
    }
  }
}

// ---------------------------------------------------------------------------
// Generic batched NT fp16 GEMM (128x128 tile, 2-phase) — kept for PV, where
// the 256x256 grid would be only 128 blocks (half the CUs idle).
// C[z][m][n] = alpha * sum_k A[z][m][k]*B[z][n][k]
template <int OUT_F16>
__global__ __launch_bounds__(256, 2)
void gemm_nt(const f16* __restrict__ A, const f16* __restrict__ Bm,
             void* __restrict__ C, int lda, int ldb, int ldc, int K,
             long sA, long sB, long sC, float alpha) {
  __shared__ __align__(16) f16 As[2 * 128 * 32];
  __shared__ __align__(16) f16 Bs[2 * 128 * 32];
  const int t = threadIdx.x;
  const int wave = t >> 6, lane = t & 63;
  const int quad = lane >> 4, l16 = lane & 15;
  const int wm = (wave & 1) * 64, wn = (wave >> 1) * 64;
  const f16* Ab = A + blockIdx.z * sA + (long)blockIdx.x * 128 * lda;
  const f16* Bb = Bm + blockIdx.z * sB + (long)blockIdx.y * 128 * ldb;
  const int r0 = t >> 2, c8 = (t & 3) * 8;
  f32x4 acc[4][4] = {};
  for (int k0 = 0; k0 < K; k0 += 64) {
    __syncthreads();
    stage16(Ab + (long)r0 * lda + k0 + c8,             As + t * 8);
    stage16(Ab + (long)(r0 + 64) * lda + k0 + c8,      As + 2048 + t * 8);
    stage16(Ab + (long)r0 * lda + k0 + 32 + c8,        As + 4096 + t * 8);
    stage16(Ab + (long)(r0 + 64) * lda + k0 + 32 + c8, As + 6144 + t * 8);
    stage16(Bb + (long)r0 * ldb + k0 + c8,             Bs + t * 8);
    stage16(Bb + (long)(r0 + 64) * ldb + k0 + c8,      Bs + 2048 + t * 8);
    stage16(Bb + (long)r0 * ldb + k0 + 32 + c8,        Bs + 4096 + t * 8);
    stage16(Bb + (long)(r0 + 64) * ldb + k0 + 32 + c8, Bs + 6144 + t * 8);
    __syncthreads();
#pragma unroll
    for (int kk = 0; kk < 2; kk++) {
      f16x8 af[4], bf[4];
#pragma unroll
      for (int i = 0; i < 4; i++) {
        af[i] = *(const f16x8*)&As[kk * 4096 + (wm + i * 16 + l16) * 32 + quad * 8];
        bf[i] = *(const f16x8*)&Bs[kk * 4096 + (wn + i * 16 + l16) * 32 + quad * 8];
      }
#pragma unroll
      for (int i = 0; i < 4; i++)
#pragma unroll
        for (int j = 0; j < 4; j++)
          acc[i][j] = __builtin_amdgcn_mfma_f32_16x16x32_f16(af[i], bf[j], acc[i][j], 0, 0, 0);
    }
  }
  const long mb = (long)blockIdx.x * 128 + wm;
  const long nb = (long)blockIdx.y * 128 + wn;
#pragma unroll
  for (int i = 0; i < 4; i++)
#pragma unroll
    for (int j = 0; j < 4; j++) {
      long m = mb + i * 16 + quad * 4;
      long n = nb + j * 16 + l16;
#pragma unroll
      for (int r = 0; r < 4; r++) {
        float v = acc[i][j][r] * alpha;
        if (OUT_F16)
          ((f16*)C)[blockIdx.z * sC + (m + r) * ldc + n] = (f16)v;
        else
          ((float*)C)[blockIdx.z * sC + (m + r) * ldc + n] = v;
      }
    }
}

// ---------------------------------------------------------------------------
// In-place row softmax over 2048 fp16 scores + quantize to fp16.
__global__ __launch_bounds__(256) void softmax_q(f16* __restrict__ sc) {
  const long row = blockIdx.x;
  f16* p = sc + row * S_;
  const int t = threadIdx.x;
  const int wave = t >> 6, lane = t & 63;
  f16x8 v = ((const f16x8*)p)[t];
  float f[8];
  float m = -3.0e38f;
#pragma unroll
  for (int c = 0; c < 8; c++) { f[c] = (float)v[c]; m = fmaxf(m, f[c]); }
#pragma unroll
  for (int o = 32; o > 0; o >>= 1) m = fmaxf(m, __shfl_xor(m, o));
  __shared__ float redm[4], reds[4];
  if (lane == 0) redm[wave] = m;
  __syncthreads();
  m = fmaxf(fmaxf(redm[0], redm[1]), fmaxf(redm[2], redm[3]));
  float s = 0.f, e[8];
#pragma unroll
  for (int c = 0; c < 8; c++) { e[c] = __expf(f[c] - m); s += e[c]; }
#pragma unroll
  for (int o = 32; o > 0; o >>= 1) s += __shfl_xor(s, o);
  if (lane == 0) reds[wave] = s;
  __syncthreads();
  s = reds[0] + reds[1] + reds[2] + reds[3];
  float inv = 1.0f / s;
  f16x8 ov;
#pragma unroll
  for (int c = 0; c < 8; c++) ov[c] = (f16)(e[c] * inv);
  ((f16x8*)p)[t] = ov;
}

// ---------------------------------------------------------------------------
extern "C" void kernel_launch(void* const* d_in, const int* in_sizes, int n_in,
                              void* d_out, int out_size, void* d_ws, size_t ws_size,
                              hipStream_t stream) {
  (void)in_sizes; (void)n_in; (void)out_size; (void)ws_size;
  const float* x  = (const float*)d_in[0];
  const float* Wq = (const float*)d_in[1];
  const float* bq = (const float*)d_in[2];
  const float* Wk = (const float*)d_in[3];
  const float* bk = (const float*)d_in[4];
  const float* Wv = (const float*)d_in[5];
  const float* bv = (const float*)d_in[6];

  char* ws = (char*)d_ws;
  f16* xh  = (f16*)ws; ws += (size_t)M_ * H_ * 2;          // 16 MiB
  f16* Wh  = (f16*)ws; ws += (size_t)3 * H_ * H_ * 2;      // 6 MiB
  f16* qkv = (f16*)ws; ws += (size_t)2 * M_ * H_ * 2;      // 32 MiB (q, k)
  f16* vT  = (f16*)ws; ws += (size_t)B_ * H_ * S_ * 2;     // 16 MiB
  f16* sc  = (f16*)ws; ws += (size_t)B_ * S_ * S_ * 2;     // 32 MiB (scores, then attn in-place)

  // 1) x, Wq/Wk/Wv -> fp16 in one launch
  downconvert_all<<<M_ * H_ / 1024 + 3 * H_ * H_ / 1024, 256, 0, stream>>>(
      x, Wq, Wk, Wv, xh, Wh);

  // 2) fused QKV projection + bias + quantize; V written transposed.
  //    256^2-tile 8-wave phase-interleaved kernel: grid 32 (M) x 12 (3 sel x 4 N).
  gemm8p<1><<<dim3(32, 12), 512, 0, stream>>>(
      xh, Wh, bq, bk, bv, qkv, vT, 0.f);

  // 3) scores = quantize(q @ k^T / 32), per batch: grid 8 x 8 x 4 = 256 blocks.
  gemm8p<0><<<dim3(8, 8, 4), 512, 0, stream>>>(
      qkv, qkv + (size_t)M_ * H_, nullptr, nullptr, nullptr, sc, nullptr,
      0.03125f);

  // 4) attn = quantize(softmax(scores)) in-place
  softmax_q<<<M_, 256, 0, stream>>>(sc);

  // 5) out = attn @ vT^T  (fp32 epilogue straight to d_out)
  gemm_nt<0><<<dim3(16, 8, 4), 256, 0, stream>>>(
      sc, vT, d_out, S_, S_, H_, S_,
      (long)S_ * S_, (long)H_ * S_, (long)S_ * H_, 1.0f);
}